// Round 12
// baseline (156.368 us; speedup 1.0000x reference)
//
#include <hip/hip_runtime.h>
#include <hip/hip_bf16.h>

#define TEMP_INV 14.285714285714286f  // 1/0.07
#define FSCALE 16.0f                  // fp8 pre-scale per operand
#define T1S (TEMP_INV / 256.0f)       // acc = 256*sim -> (sim-1)/T = acc*T1S - TEMP_INV

typedef __attribute__((ext_vector_type(4))) float f32x4;
typedef __attribute__((ext_vector_type(4))) int i32x4;
typedef __attribute__((ext_vector_type(8))) int i32x8;

// ---- fq FRAGMENT-MAJOR layout ----
// 2KB tiles: tile(rg, kb), rg = row/16, kb = kbyte/128. Fragment (lane) =
// lo16B at tile+lane*16, hi16B at tile+1024+lane*16 -> two lane-consecutive
// 1KB global loads per fragment.

// ---- row L2-normalize -> fp8 e4m3 (x16) into fragment-major layout ----
__global__ __launch_bounds__(256) void norm_k(const float* __restrict__ feat,
                                              uchar* __restrict__ fq,
                                              const int* __restrict__ labels,
                                              const int* __restrict__ kptr,
                                              int* __restrict__ glab,
                                              float* __restrict__ gacc,
                                              int* __restrict__ dcnt,
                                              int N, int D) {
  const int row = (blockIdx.x * 256 + threadIdx.x) >> 6;
  const int lane = threadIdx.x & 63;
  if (row < N) {
    const float4* fr = (const float4*)(feat + (size_t)row * D);
    float4 v0 = fr[lane * 2];
    float4 v1 = fr[lane * 2 + 1];
    float ss = v0.x * v0.x + v0.y * v0.y + v0.z * v0.z + v0.w * v0.w +
               v1.x * v1.x + v1.y * v1.y + v1.z * v1.z + v1.w * v1.w;
    #pragma unroll
    for (int off = 32; off; off >>= 1) ss += __shfl_xor(ss, off, 64);
    const float inv = FSCALE / fmaxf(sqrtf(ss), 1e-12f);
    int w0 = 0, w1 = 0;
    w0 = __builtin_amdgcn_cvt_pk_fp8_f32(v0.x * inv, v0.y * inv, w0, false);
    w0 = __builtin_amdgcn_cvt_pk_fp8_f32(v0.z * inv, v0.w * inv, w0, true);
    w1 = __builtin_amdgcn_cvt_pk_fp8_f32(v1.x * inv, v1.y * inv, w1, false);
    w1 = __builtin_amdgcn_cvt_pk_fp8_f32(v1.z * inv, v1.w * inv, w1, true);
    uint2 o; o.x = (uint)w0; o.y = (uint)w1;
    const int tkb  = lane >> 4;
    const int quad = (lane >> 2) & 3;
    const int half = (lane >> 1) & 1;
    const int slot = half * 64 + quad * 16 + (row & 15);
    uchar* dstp = fq + (((size_t)(row >> 4) * (D >> 7) + tkb) << 11) +
                  slot * 16 + (lane & 1) * 8;
    *(uint2*)dstp = o;
    if (lane == 0) {
      const int k = *kptr;
      glab[row] = labels[(size_t)(row / k) * k];
    }
  }
  if (blockIdx.x == 0 && threadIdx.x < 3) {
    if (threadIdx.x < 2) gacc[threadIdx.x] = 0.f;
    else *dcnt = 0;
  }
}

// ---- flash-style fused GEMM + online masked-softmax stats ----
// r25 = r21 (best measured) + kt-granularity B-PREFETCH rotation.
// Named X/Y quad-buffers, kt fully unrolled so X/Y parity is static:
//   load Y(kt1) ; MFMA(X,kt0) ; load X(kt2) ; MFMA(Y,kt1) ;
//   load Y(kt3) ; MFMA(X,kt2) ; load X(js+1,kt0) ; MFMA(Y,kt3) ; EPILOG(js)
// Every 4-LOADF cluster (8 global_load_dwordx4) now flies under 8 MFMAs
// (+ the epilogue at js boundaries) instead of serializing before its own
// MFMAs. +64 VGPR for the double-buffer; __launch_bounds__(128,2) caps VGPR
// at 256 so 2 waves/SIMD stay resident.
__global__ __launch_bounds__(128, 2) void gemm_k(const uchar* __restrict__ fq,
                                                 const int* __restrict__ glab,
                                                 float* __restrict__ partS,
                                                 float* __restrict__ partP,
                                                 int N, int D) {
  const int lane = threadIdx.x & 63;
  const int wid  = threadIdx.x >> 6;
  const int quad = lane >> 4, l15 = lane & 15;
  const int ktiles = D >> 7;              // 4 at D=512
  const int strip = (blockIdx.x >> 3) * 2 + wid;   // 0..N/32-1
  const int slice = blockIdx.x & 7;                // XCD-pinned col slice
  const int r0 = strip * 32;
  const int cps = N >> 3;                 // cols per slice (1024)
  const int jsteps = cps >> 6;            // 16
  const int j0base = slice * cps;

  int rlab[2][4];
  #pragma unroll
  for (int mi = 0; mi < 2; mi++)
    #pragma unroll
    for (int r = 0; r < 4; r++)
      rlab[mi][r] = glab[r0 + mi * 16 + quad * 4 + r];

  float Srun[2][4] = {{0.f, 0.f, 0.f, 0.f}, {0.f, 0.f, 0.f, 0.f}};
  float Prun[2][4] = {{0.f, 0.f, 0.f, 0.f}, {0.f, 0.f, 0.f, 0.f}};

#define LOADF(dst, grp, kt)                                                   \
  {                                                                           \
    const uchar* p_ = fq + (((size_t)((grp) * ktiles + (kt))) << 11) + lane * 16; \
    i32x4* d_ = (i32x4*)&(dst);                                               \
    d_[0] = *(const i32x4*)p_;                                                \
    d_[1] = *(const i32x4*)(p_ + 1024);                                       \
  }

#define LOADB4(B0, B1, B2, B3, j0, kt)                                        \
  LOADF(B0, ((j0) >> 4) + 0, kt) LOADF(B1, ((j0) >> 4) + 1, kt)               \
  LOADF(B2, ((j0) >> 4) + 2, kt) LOADF(B3, ((j0) >> 4) + 3, kt)

#define MFMA8(B0, B1, B2, B3, kt)                                             \
  _Pragma("unroll")                                                           \
  for (int mi = 0; mi < 2; mi++) {                                            \
    acc[mi][0] = __builtin_amdgcn_mfma_scale_f32_16x16x128_f8f6f4(            \
        af[mi][kt], B0, acc[mi][0], 0, 0, 0, 127, 0, 127);                    \
    acc[mi][1] = __builtin_amdgcn_mfma_scale_f32_16x16x128_f8f6f4(            \
        af[mi][kt], B1, acc[mi][1], 0, 0, 0, 127, 0, 127);                    \
    acc[mi][2] = __builtin_amdgcn_mfma_scale_f32_16x16x128_f8f6f4(            \
        af[mi][kt], B2, acc[mi][2], 0, 0, 0, 127, 0, 127);                    \
    acc[mi][3] = __builtin_amdgcn_mfma_scale_f32_16x16x128_f8f6f4(            \
        af[mi][kt], B3, acc[mi][3], 0, 0, 0, 127, 0, 127);                    \
  }

#define EPILOG(j0)                                                            \
  {                                                                           \
    int clab[4];                                                              \
    _Pragma("unroll")                                                         \
    for (int ni = 0; ni < 4; ni++) clab[ni] = glab[(j0) + ni * 16 + l15];     \
    _Pragma("unroll")                                                         \
    for (int mi = 0; mi < 2; mi++)                                            \
      _Pragma("unroll")                                                       \
      for (int r = 0; r < 4; r++) {                                           \
        const int row = r0 + mi * 16 + quad * 4 + r;                          \
        const int rl = rlab[mi][r];                                           \
        float s = 0.f, pp = 0.f;                                              \
        _Pragma("unroll")                                                     \
        for (int ni = 0; ni < 4; ni++) {                                      \
          const int col = (j0) + ni * 16 + l15;                               \
          const float lg = fmaf(acc[mi][ni][r], T1S, -TEMP_INV);              \
          const bool diag = (col == row);                                     \
          s += diag ? 0.f : __expf(lg);                                       \
          pp += (!diag && rl == clab[ni]) ? lg : 0.f;                         \
        }                                                                     \
        Srun[mi][r] += s;                                                     \
        Prun[mi][r] += pp;                                                    \
      }                                                                       \
  }

  if (ktiles == 4) {
    // A-fragments register-cached once for the whole strip
    i32x8 af[2][4];
    #pragma unroll
    for (int mi = 0; mi < 2; mi++)
      #pragma unroll
      for (int kt = 0; kt < 4; kt++)
        LOADF(af[mi][kt], (r0 >> 4) + mi, kt)

    i32x8 bX0, bX1, bX2, bX3, bY0, bY1, bY2, bY3;
    LOADB4(bX0, bX1, bX2, bX3, j0base, 0)   // prologue: (js=0, kt=0)

    for (int js = 0; js < jsteps; js++) {
      const int j0 = j0base + js * 64;
      f32x4 acc[2][4];
      #pragma unroll
      for (int mi = 0; mi < 2; mi++)
        #pragma unroll
        for (int ni = 0; ni < 4; ni++) {
          f32x4 z = {0.f, 0.f, 0.f, 0.f};
          acc[mi][ni] = z;
        }
      LOADB4(bY0, bY1, bY2, bY3, j0, 1)
      MFMA8(bX0, bX1, bX2, bX3, 0)
      LOADB4(bX0, bX1, bX2, bX3, j0, 2)
      MFMA8(bY0, bY1, bY2, bY3, 1)
      LOADB4(bY0, bY1, bY2, bY3, j0, 3)
      MFMA8(bX0, bX1, bX2, bX3, 2)
      if (js + 1 < jsteps) {
        LOADB4(bX0, bX1, bX2, bX3, j0 + 64, 0)   // next js, kt0
      }
      MFMA8(bY0, bY1, bY2, bY3, 3)
      EPILOG(j0)
    }
  } else {
    // generic fallback: stream A and B per k-tile (D != 512)
    for (int js = 0; js < jsteps; js++) {
      const int j0 = j0base + js * 64;
      f32x4 acc[2][4];
      #pragma unroll
      for (int mi = 0; mi < 2; mi++)
        #pragma unroll
        for (int ni = 0; ni < 4; ni++) {
          f32x4 z = {0.f, 0.f, 0.f, 0.f};
          acc[mi][ni] = z;
        }
      for (int kt = 0; kt < ktiles; kt++) {
        i32x8 af[2][4];  // only [*][0] used per kt in fallback
        LOADF(af[0][0], (r0 >> 4) + 0, kt)
        LOADF(af[1][0], (r0 >> 4) + 1, kt)
        i32x8 bv[4];
        #pragma unroll
        for (int ni = 0; ni < 4; ni++)
          LOADF(bv[ni], (j0 >> 4) + ni, kt)
        #pragma unroll
        for (int mi = 0; mi < 2; mi++)
          #pragma unroll
          for (int ni = 0; ni < 4; ni++)
            acc[mi][ni] = __builtin_amdgcn_mfma_scale_f32_16x16x128_f8f6f4(
                af[mi][0], bv[ni], acc[mi][ni], 0, 0, 0, 127, 0, 127);
      }
      EPILOG(j0)
    }
  }
#undef LOADF
#undef LOADB4
#undef MFMA8
#undef EPILOG

  // one shuffle-reduce per strip
  #pragma unroll
  for (int mi = 0; mi < 2; mi++)
    #pragma unroll
    for (int r = 0; r < 4; r++) {
      float s = Srun[mi][r], p = Prun[mi][r];
      #pragma unroll
      for (int off = 1; off < 16; off <<= 1) {
        s += __shfl_xor(s, off, 64);
        p += __shfl_xor(p, off, 64);
      }
      if (l15 == 0) {
        const int row = r0 + mi * 16 + quad * 4 + r;
        partS[(size_t)row * 8 + slice] = s;
        partP[(size_t)row * 8 + slice] = p;
      }
    }
}

// ---- per-row slice-sum + histogram -> loss ----
__global__ __launch_bounds__(256) void reduce_loss_k(const float* __restrict__ partS,
                                                     const float* __restrict__ partP,
                                                     const int* __restrict__ glab,
                                                     const int* __restrict__ labels,
                                                     const int* __restrict__ kptr,
                                                     float* __restrict__ gacc,
                                                     int* __restrict__ dcnt,
                                                     float* __restrict__ out, int N) {
  const int tt = threadIdx.x;
  const int row = blockIdx.x * 256 + tt;
  const int k = *kptr;
  const int B = N / k;

  __shared__ int h[64];
  if (tt < 64) h[tt] = 0;
  __syncthreads();
  for (int g = tt; g < B; g += 256) {
    int lb = labels[(size_t)g * k];
    if (lb >= 0 && lb < 64) atomicAdd(&h[lb], 1);
  }
  __syncthreads();

  float l = 0.f, v = 0.f;
  if (row < N) {
    float S = 0.f, P = 0.f;
    #pragma unroll
    for (int s = 0; s < 8; s++) {
      S += partS[(size_t)row * 8 + s];
      P += partP[(size_t)row * 8 + s];
    }
    const int np = h[glab[row]] * k - 1;
    if (np > 0) {
      l = -(P - (float)np * logf(S + 1e-8f)) / (float)np;
      v = 1.f;
    }
  }
  #pragma unroll
  for (int off = 32; off; off >>= 1) {
    l += __shfl_xor(l, off, 64);
    v += __shfl_xor(v, off, 64);
  }
  __shared__ float sl4[4], sv4[4];
  if ((tt & 63) == 0) { sl4[tt >> 6] = l; sv4[tt >> 6] = v; }
  __syncthreads();
  if (tt == 0) {
    float L = 0.f, V = 0.f;
    #pragma unroll
    for (int i = 0; i < 4; i++) { L += sl4[i]; V += sv4[i]; }
    atomicAdd(&gacc[0], L);
    atomicAdd(&gacc[1], V);
    __threadfence();
    const int prev = atomicAdd(dcnt, 1);
    if (prev == (int)gridDim.x - 1) {
      const float Lf = atomicAdd(&gacc[0], 0.f);
      const float Vf = atomicAdd(&gacc[1], 0.f);
      out[0] = Lf / fmaxf(Vf, 1.f);
    }
  }
}

extern "C" void kernel_launch(void* const* d_in, const int* in_sizes, int n_in,
                              void* d_out, int out_size, void* d_ws, size_t ws_size,
                              hipStream_t stream) {
  const float* feat = (const float*)d_in[0];
  const int* labels = (const int*)d_in[1];
  const int* kptr   = (const int*)d_in[2];
  const int N = in_sizes[1];
  const int D = in_sizes[0] / N;  // 512

  char* ws = (char*)d_ws;
  uchar* fq = (uchar*)ws;
  size_t off = (size_t)N * D;  // fp8: 1 byte/elem
  float* partS = (float*)(ws + off); off += (size_t)N * 8 * sizeof(float);
  float* partP = (float*)(ws + off); off += (size_t)N * 8 * sizeof(float);
  int* glab    = (int*)(ws + off);   off += (size_t)N * sizeof(int);
  float* gacc  = (float*)(ws + off); off += 2 * sizeof(float);
  int* dcnt    = (int*)(ws + off);   off += sizeof(int);

  const int strips = N / 32;            // 256
  const int ggrid = (strips / 2) * 8;   // 1024 blocks x 128 threads

  norm_k<<<(N + 3) / 4, 256, 0, stream>>>(feat, fq, labels, kptr, glab,
                                          gacc, dcnt, N, D);
  gemm_k<<<ggrid, 128, 0, stream>>>(fq, glab, partS, partP, N, D);
  reduce_loss_k<<<(N + 255) / 256, 256, 0, stream>>>(partS, partP, glab, labels,
                                                     kptr, gacc, dcnt,
                                                     (float*)d_out, N);
}

// Round 13
// 125.507 us; speedup vs baseline: 1.2459x; 1.2459x over previous
//
#include <hip/hip_runtime.h>
#include <hip/hip_bf16.h>

#define TEMP_INV 14.285714285714286f  // 1/0.07
#define FSCALE 16.0f                  // fp8 pre-scale per operand
#define T1S (TEMP_INV / 256.0f)       // acc = 256*sim -> (sim-1)/T = acc*T1S - TEMP_INV

typedef __attribute__((ext_vector_type(4))) float f32x4;
typedef __attribute__((ext_vector_type(4))) int i32x4;
typedef __attribute__((ext_vector_type(8))) int i32x8;

// ---- fq FRAGMENT-MAJOR layout ----
// fq is organized in 2KB tiles: tile(rg, kb) with rg = row/16, kb = kbyte/128.
// Within a tile, byte (row r16, k-offset o in [0,128)) lives at:
//   slot = ((o>>4)&1)*64 + (o>>5)*16 + r16 ;  addr = slot*16 + (o&15)
// An MFMA fragment (lane = quad*16+l15 wants row l15, k = quad*32..+32)
// reads lo16B at tile+lane*16, hi16B at tile+1024+lane*16 -> two perfectly
// lane-consecutive 1KB global loads per fragment.

// ---- row L2-normalize -> fp8 e4m3 (x16) into fragment-major layout ----
__global__ __launch_bounds__(256) void norm_k(const float* __restrict__ feat,
                                              uchar* __restrict__ fq,
                                              const int* __restrict__ labels,
                                              const int* __restrict__ kptr,
                                              int* __restrict__ glab,
                                              float* __restrict__ gacc,
                                              int* __restrict__ dcnt,
                                              int N, int D) {
  const int row = (blockIdx.x * 256 + threadIdx.x) >> 6;
  const int lane = threadIdx.x & 63;
  if (row < N) {
    const float4* fr = (const float4*)(feat + (size_t)row * D);
    float4 v0 = fr[lane * 2];
    float4 v1 = fr[lane * 2 + 1];
    float ss = v0.x * v0.x + v0.y * v0.y + v0.z * v0.z + v0.w * v0.w +
               v1.x * v1.x + v1.y * v1.y + v1.z * v1.z + v1.w * v1.w;
    #pragma unroll
    for (int off = 32; off; off >>= 1) ss += __shfl_xor(ss, off, 64);
    const float inv = FSCALE / fmaxf(sqrtf(ss), 1e-12f);
    int w0 = 0, w1 = 0;
    w0 = __builtin_amdgcn_cvt_pk_fp8_f32(v0.x * inv, v0.y * inv, w0, false);
    w0 = __builtin_amdgcn_cvt_pk_fp8_f32(v0.z * inv, v0.w * inv, w0, true);
    w1 = __builtin_amdgcn_cvt_pk_fp8_f32(v1.x * inv, v1.y * inv, w1, false);
    w1 = __builtin_amdgcn_cvt_pk_fp8_f32(v1.z * inv, v1.w * inv, w1, true);
    uint2 o; o.x = (uint)w0; o.y = (uint)w1;
    // lane covers kbytes [lane*8, lane*8+8) of this row
    const int tkb  = lane >> 4;          // k-block tile
    const int quad = (lane >> 2) & 3;    // (kbyte%128)>>5
    const int half = (lane >> 1) & 1;    // (kbyte%32)>>4
    const int slot = half * 64 + quad * 16 + (row & 15);
    uchar* dstp = fq + (((size_t)(row >> 4) * (D >> 7) + tkb) << 11) +
                  slot * 16 + (lane & 1) * 8;
    *(uint2*)dstp = o;
    if (lane == 0) {
      const int k = *kptr;
      glab[row] = labels[(size_t)(row / k) * k];
    }
  }
  if (blockIdx.x == 0 && threadIdx.x < 3) {
    if (threadIdx.x < 2) gacc[threadIdx.x] = 0.f;
    else *dcnt = 0;
  }
}

// ---- flash-style fused GEMM + online masked-softmax stats ----
// r26 = exact r21 (session best: 125.7us total, gemm 57.0us).
// Each WAVE owns a 32-row strip and loops a 1024-col slice (16 j-steps of
// 64 cols, FULL matrix -> no col-side partials, no triangle decode).
// A-fragments (strip x D) register-cached ONCE (64 VGPR), reused 16x.
// Per j-step: 16 coalesced B-loads + 32 MFMA + pure-VALU online S/P accum
// (no shuffles, no stores). Shuffle-reduce + part store ONCE per strip.
// slice = blockIdx&7 pins each B-slice to one XCD's L2.
// 2 waves/block (no shared state, no barriers), grid = (N/64)*8 = 1024.
__global__ __launch_bounds__(128) void gemm_k(const uchar* __restrict__ fq,
                                              const int* __restrict__ glab,
                                              float* __restrict__ partS,
                                              float* __restrict__ partP,
                                              int N, int D) {
  const int lane = threadIdx.x & 63;
  const int wid  = threadIdx.x >> 6;
  const int quad = lane >> 4, l15 = lane & 15;
  const int ktiles = D >> 7;              // 4 at D=512
  const int strip = (blockIdx.x >> 3) * 2 + wid;   // 0..N/32-1
  const int slice = blockIdx.x & 7;                // XCD-pinned col slice
  const int r0 = strip * 32;
  const int cps = N >> 3;                 // cols per slice (1024)
  const int jsteps = cps >> 6;            // 16
  const int j0base = slice * cps;

  // per-lane labels for this strip's rows (row = r0 + mi*16 + quad*4 + r)
  int rlab[2][4];
  #pragma unroll
  for (int mi = 0; mi < 2; mi++)
    #pragma unroll
    for (int r = 0; r < 4; r++)
      rlab[mi][r] = glab[r0 + mi * 16 + quad * 4 + r];

  float Srun[2][4] = {{0.f, 0.f, 0.f, 0.f}, {0.f, 0.f, 0.f, 0.f}};
  float Prun[2][4] = {{0.f, 0.f, 0.f, 0.f}, {0.f, 0.f, 0.f, 0.f}};

#define LOADF(dst, grp, kt)                                                   \
  {                                                                           \
    const uchar* p_ = fq + (((size_t)((grp) * ktiles + (kt))) << 11) + lane * 16; \
    i32x4 lo_ = *(const i32x4*)p_;                                            \
    i32x4 hi_ = *(const i32x4*)(p_ + 1024);                                   \
    dst = (i32x8){lo_.x, lo_.y, lo_.z, lo_.w, hi_.x, hi_.y, hi_.z, hi_.w};    \
  }

  if (ktiles == 4) {
    // A-fragments register-cached once for the whole strip
    i32x8 af[2][4];
    #pragma unroll
    for (int mi = 0; mi < 2; mi++)
      #pragma unroll
      for (int kt = 0; kt < 4; kt++)
        LOADF(af[mi][kt], (r0 >> 4) + mi, kt)

    for (int js = 0; js < jsteps; js++) {
      const int j0 = j0base + js * 64;
      f32x4 acc[2][4];
      #pragma unroll
      for (int mi = 0; mi < 2; mi++)
        #pragma unroll
        for (int ni = 0; ni < 4; ni++) {
          f32x4 z = {0.f, 0.f, 0.f, 0.f};
          acc[mi][ni] = z;
        }
      #pragma unroll
      for (int kt = 0; kt < 4; kt++) {
        i32x8 bv[4];
        #pragma unroll
        for (int ni = 0; ni < 4; ni++)
          LOADF(bv[ni], (j0 >> 4) + ni, kt)
        #pragma unroll
        for (int mi = 0; mi < 2; mi++)
          #pragma unroll
          for (int ni = 0; ni < 4; ni++)
            acc[mi][ni] = __builtin_amdgcn_mfma_scale_f32_16x16x128_f8f6f4(
                af[mi][kt], bv[ni], acc[mi][ni], 0, 0, 0, 127, 0, 127);
      }
      int clab[4];
      #pragma unroll
      for (int ni = 0; ni < 4; ni++) clab[ni] = glab[j0 + ni * 16 + l15];
      #pragma unroll
      for (int mi = 0; mi < 2; mi++)
        #pragma unroll
        for (int r = 0; r < 4; r++) {
          const int row = r0 + mi * 16 + quad * 4 + r;
          const int rl = rlab[mi][r];
          float s = 0.f, pp = 0.f;
          #pragma unroll
          for (int ni = 0; ni < 4; ni++) {
            const int col = j0 + ni * 16 + l15;
            const float lg = fmaf(acc[mi][ni][r], T1S, -TEMP_INV);
            const bool diag = (col == row);
            s += diag ? 0.f : __expf(lg);
            pp += (!diag && rl == clab[ni]) ? lg : 0.f;
          }
          Srun[mi][r] += s;
          Prun[mi][r] += pp;
        }
    }
  } else {
    // generic fallback: stream A per k-tile (D != 512)
    for (int js = 0; js < jsteps; js++) {
      const int j0 = j0base + js * 64;
      f32x4 acc[2][4];
      #pragma unroll
      for (int mi = 0; mi < 2; mi++)
        #pragma unroll
        for (int ni = 0; ni < 4; ni++) {
          f32x4 z = {0.f, 0.f, 0.f, 0.f};
          acc[mi][ni] = z;
        }
      for (int kt = 0; kt < ktiles; kt++) {
        i32x8 as[2], bv[4];
        #pragma unroll
        for (int mi = 0; mi < 2; mi++) LOADF(as[mi], (r0 >> 4) + mi, kt)
        #pragma unroll
        for (int ni = 0; ni < 4; ni++) LOADF(bv[ni], (j0 >> 4) + ni, kt)
        #pragma unroll
        for (int mi = 0; mi < 2; mi++)
          #pragma unroll
          for (int ni = 0; ni < 4; ni++)
            acc[mi][ni] = __builtin_amdgcn_mfma_scale_f32_16x16x128_f8f6f4(
                as[mi], bv[ni], acc[mi][ni], 0, 0, 0, 127, 0, 127);
      }
      int clab[4];
      #pragma unroll
      for (int ni = 0; ni < 4; ni++) clab[ni] = glab[j0 + ni * 16 + l15];
      #pragma unroll
      for (int mi = 0; mi < 2; mi++)
        #pragma unroll
        for (int r = 0; r < 4; r++) {
          const int row = r0 + mi * 16 + quad * 4 + r;
          const int rl = rlab[mi][r];
          float s = 0.f, pp = 0.f;
          #pragma unroll
          for (int ni = 0; ni < 4; ni++) {
            const int col = j0 + ni * 16 + l15;
            const float lg = fmaf(acc[mi][ni][r], T1S, -TEMP_INV);
            const bool diag = (col == row);
            s += diag ? 0.f : __expf(lg);
            pp += (!diag && rl == clab[ni]) ? lg : 0.f;
          }
          Srun[mi][r] += s;
          Prun[mi][r] += pp;
        }
    }
  }
#undef LOADF

  // ONE shuffle-reduce per strip: sum over the 16 lanes (l15) of each quad
  #pragma unroll
  for (int mi = 0; mi < 2; mi++)
    #pragma unroll
    for (int r = 0; r < 4; r++) {
      float s = Srun[mi][r], p = Prun[mi][r];
      #pragma unroll
      for (int off = 1; off < 16; off <<= 1) {
        s += __shfl_xor(s, off, 64);
        p += __shfl_xor(p, off, 64);
      }
      if (l15 == 0) {
        const int row = r0 + mi * 16 + quad * 4 + r;
        partS[(size_t)row * 8 + slice] = s;
        partP[(size_t)row * 8 + slice] = p;
      }
    }
}

// ---- per-row slice-sum + histogram -> loss ----
__global__ __launch_bounds__(256) void reduce_loss_k(const float* __restrict__ partS,
                                                     const float* __restrict__ partP,
                                                     const int* __restrict__ glab,
                                                     const int* __restrict__ labels,
                                                     const int* __restrict__ kptr,
                                                     float* __restrict__ gacc,
                                                     int* __restrict__ dcnt,
                                                     float* __restrict__ out, int N) {
  const int tt = threadIdx.x;
  const int row = blockIdx.x * 256 + tt;
  const int k = *kptr;
  const int B = N / k;

  __shared__ int h[64];
  if (tt < 64) h[tt] = 0;
  __syncthreads();
  for (int g = tt; g < B; g += 256) {
    int lb = labels[(size_t)g * k];
    if (lb >= 0 && lb < 64) atomicAdd(&h[lb], 1);
  }
  __syncthreads();

  float l = 0.f, v = 0.f;
  if (row < N) {
    float S = 0.f, P = 0.f;
    #pragma unroll
    for (int s = 0; s < 8; s++) {
      S += partS[(size_t)row * 8 + s];
      P += partP[(size_t)row * 8 + s];
    }
    const int np = h[glab[row]] * k - 1;
    if (np > 0) {
      l = -(P - (float)np * logf(S + 1e-8f)) / (float)np;
      v = 1.f;
    }
  }
  #pragma unroll
  for (int off = 32; off; off >>= 1) {
    l += __shfl_xor(l, off, 64);
    v += __shfl_xor(v, off, 64);
  }
  __shared__ float sl4[4], sv4[4];
  if ((tt & 63) == 0) { sl4[tt >> 6] = l; sv4[tt >> 6] = v; }
  __syncthreads();
  if (tt == 0) {
    float L = 0.f, V = 0.f;
    #pragma unroll
    for (int i = 0; i < 4; i++) { L += sl4[i]; V += sv4[i]; }
    atomicAdd(&gacc[0], L);
    atomicAdd(&gacc[1], V);
    __threadfence();
    const int prev = atomicAdd(dcnt, 1);
    if (prev == (int)gridDim.x - 1) {
      const float Lf = atomicAdd(&gacc[0], 0.f);
      const float Vf = atomicAdd(&gacc[1], 0.f);
      out[0] = Lf / fmaxf(Vf, 1.f);
    }
  }
}

extern "C" void kernel_launch(void* const* d_in, const int* in_sizes, int n_in,
                              void* d_out, int out_size, void* d_ws, size_t ws_size,
                              hipStream_t stream) {
  const float* feat = (const float*)d_in[0];
  const int* labels = (const int*)d_in[1];
  const int* kptr   = (const int*)d_in[2];
  const int N = in_sizes[1];
  const int D = in_sizes[0] / N;  // 512

  char* ws = (char*)d_ws;
  uchar* fq = (uchar*)ws;
  size_t off = (size_t)N * D;  // fp8: 1 byte/elem
  float* partS = (float*)(ws + off); off += (size_t)N * 8 * sizeof(float);
  float* partP = (float*)(ws + off); off += (size_t)N * 8 * sizeof(float);
  int* glab    = (int*)(ws + off);   off += (size_t)N * sizeof(int);
  float* gacc  = (float*)(ws + off); off += 2 * sizeof(float);
  int* dcnt    = (int*)(ws + off);   off += sizeof(int);

  const int strips = N / 32;            // 256
  const int ggrid = (strips / 2) * 8;   // 1024 blocks x 128 threads

  norm_k<<<(N + 3) / 4, 256, 0, stream>>>(feat, fq, labels, kptr, glab,
                                          gacc, dcnt, N, D);
  gemm_k<<<ggrid, 128, 0, stream>>>(fq, glab, partS, partP, N, D);
  reduce_loss_k<<<(N + 255) / 256, 256, 0, stream>>>(partS, partP, glab, labels,
                                                     kptr, gacc, dcnt,
                                                     (float*)d_out, N);
}